// Round 6
// baseline (541.103 us; speedup 1.0000x reference)
//
#include <hip/hip_runtime.h>

// GAQN actor, fused into ONE plain (graph-capturable) kernel:
// stats -> score/argmax -> gather, with a hand-rolled device-scope grid
// barrier (monotonic counter in d_ws, zeroed by the preceding memset).
// batch_idx is SORTED -> wave-level segmented scans, one atomic per run tail.
// Exactly-resident grid: 1024 blocks x 256 thr, __launch_bounds__(256,4)
// => 4 blocks/CU x 256 CU. Spin has a timeout so a barrier failure yields
// a wrong answer, never a GPU hang.

#define N_ELEMS 1048576
#define BSEG    16384
#define NB      1024
#define NT      256
#define CHUNK   (NB * NT)          // 262144 threads
#define ITERS   (N_ELEMS / CHUNK)  // 4 elements per thread

__device__ __forceinline__ unsigned rotl32(unsigned x, unsigned r) {
    return (x << r) | (x >> (32u - r));
}

#define TF_ROUND(r) { x0 += x1; x1 = rotl32(x1, (r)); x1 ^= x0; }

// Threefry-2x32, 20 rounds, key = (0, 42)
__device__ __forceinline__ void tf2x32(unsigned x0, unsigned x1,
                                       unsigned& o0, unsigned& o1) {
    const unsigned k0 = 0u, k1 = 42u;
    const unsigned ks2 = k0 ^ k1 ^ 0x1BD11BDAu;
    x0 += k0; x1 += k1;
    TF_ROUND(13) TF_ROUND(15) TF_ROUND(26) TF_ROUND(6)
    x0 += k1; x1 += ks2 + 1u;
    TF_ROUND(17) TF_ROUND(29) TF_ROUND(16) TF_ROUND(24)
    x0 += ks2; x1 += k0 + 2u;
    TF_ROUND(13) TF_ROUND(15) TF_ROUND(26) TF_ROUND(6)
    x0 += k0; x1 += k1 + 3u;
    TF_ROUND(17) TF_ROUND(29) TF_ROUND(16) TF_ROUND(24)
    x0 += k1; x1 += ks2 + 4u;
    TF_ROUND(13) TF_ROUND(15) TF_ROUND(26) TF_ROUND(6)
    x0 += ks2; x1 += k0 + 5u;
    o0 = x0; o1 = x1;
}

// jax partitionable threefry harvest (bit-exact, verified absmax=0 R3/R4)
__device__ __forceinline__ float gumbel_val(unsigned i) {
    unsigned a, b;
    tf2x32(0u, i, a, b);
    unsigned bits = a ^ b;
    float f = __uint_as_float((bits >> 9) | 0x3f800000u) - 1.0f;
    const float tiny = 1.17549435e-38f;  // FLT_MIN
    float u = fmaxf(tiny, f + tiny);
    return -logf(-logf(u));
}

// Order-preserving float<->uint32 encode
__device__ __forceinline__ unsigned fenc(float f) {
    unsigned b = __float_as_uint(f);
    return (b & 0x80000000u) ? ~b : (b | 0x80000000u);
}
__device__ __forceinline__ float fdec(unsigned e) {
    unsigned b = (e & 0x80000000u) ? (e ^ 0x80000000u) : ~e;
    return __uint_as_float(b);
}

// Device-scope grid barrier, phase p (p = 1, 2, ...). Counter pre-zeroed by
// host-side memset. Timeout => proceed wrong rather than hang the GPU.
__device__ __forceinline__ void grid_bar(unsigned* bar, int p) {
    __syncthreads();
    if (threadIdx.x == 0) {
        __threadfence();                       // release prior writes
        atomicAdd(bar, 1u);
        const unsigned target = (unsigned)(NB * p);
        int guard = 0;
        while (__hip_atomic_load(bar, __ATOMIC_ACQUIRE,
                                 __HIP_MEMORY_SCOPE_AGENT) < target) {
            __builtin_amdgcn_s_sleep(2);
            if (++guard > 200000) break;       // ~20 ms cap: fail, don't hang
        }
        __threadfence();                       // acquire
    }
    __syncthreads();
}

__global__ __launch_bounds__(NT, 4)
void k_fused(const float4* __restrict__ cand,
             const float*  __restrict__ vals,
             const int*    __restrict__ idx,
             float4*       __restrict__ out,
             unsigned long long* __restrict__ packed,
             unsigned*     __restrict__ cnt,
             unsigned*     __restrict__ vmax,
             unsigned*     __restrict__ bar) {
    const int tid  = blockIdx.x * NT + threadIdx.x;   // 0 .. CHUNK-1
    const int lane = threadIdx.x & 63;

    // ---- Phase 1: per-segment count + value-max (segmented wave scan) ----
    int   bl[ITERS];
    float vl[ITERS];
#pragma unroll
    for (int it = 0; it < ITERS; ++it) {
        const int i = it * CHUNK + tid;
        const int   b = idx[i];
        const float v = vals[i];
        bl[it] = b; vl[it] = v;
        unsigned c = 1u;
        unsigned m = fenc(v);
#pragma unroll
        for (int d = 1; d < 64; d <<= 1) {
            int      bo = __shfl_up(b, d, 64);
            unsigned co = __shfl_up(c, d, 64);
            unsigned mo = __shfl_up(m, d, 64);
            if (lane >= d && bo == b) { c += co; if (mo > m) m = mo; }
        }
        const int bn = __shfl_down(b, 1, 64);
        if (lane == 63 || bn != b) {           // run tail -> one atomic pair
            atomicAdd(&cnt[b], c);
            atomicMax(&vmax[b], m);
        }
    }
    grid_bar(bar, 1);

    // ---- Phase 2: score = log(probs)+gumbel; segmented argmax of
    //      (enc(score)<<32 | id); max-id tiebreak matches reference ----
#pragma unroll
    for (int it = 0; it < ITERS; ++it) {
        const int i = it * CHUNK + tid;
        const int   b = bl[it];
        const float v = vl[it];
        const float vm = fdec(vmax[b]);        // wave-broadcast read
        const float c  = (float)cnt[b];
        float probs = ((v == vm) ? 1.0f : 0.0f) + 0.05f / (c - 1.0f);
        if (isinf(probs)) probs = 1.0f;        // cnt==1 -> inf -> 1
        const float score = logf(probs) + gumbel_val((unsigned)i);
        unsigned long long p = ((unsigned long long)fenc(score) << 32)
                             | (unsigned long long)(unsigned)i;
#pragma unroll
        for (int d = 1; d < 64; d <<= 1) {
            int                bo = __shfl_up(b, d, 64);
            unsigned long long po = __shfl_up(p, d, 64);
            if (lane >= d && bo == b) { if (po > p) p = po; }
        }
        const int bn = __shfl_down(b, 1, 64);
        if (lane == 63 || bn != b) atomicMax(&packed[b], p);
    }
    grid_bar(bar, 2);

    // ---- Phase 3: out row r = candidates[winner[B-1-r]] (float4 x16) ----
    {
        const int r = tid >> 4;                // CHUNK/16 == BSEG rows exactly
        const int q = tid & 15;
        const unsigned long long p = packed[BSEG - 1 - r];
        unsigned id = (unsigned)(p & 0xFFFFFFFFull);
        if (p == 0ull || id >= N_ELEMS) id = 0u;   // empty-segment fallback
        out[(size_t)r * 16 + q] = cand[(size_t)id * 16 + q];
    }
}

extern "C" void kernel_launch(void* const* d_in, const int* in_sizes, int n_in,
                              void* d_out, int out_size, void* d_ws, size_t ws_size,
                              hipStream_t stream) {
    const float4* cand = (const float4*)d_in[0];
    const float*  vals = (const float*)d_in[1];
    const int*    idx  = (const int*)d_in[2];
    float4* out = (float4*)d_out;

    unsigned long long* packed = (unsigned long long*)d_ws;   // B * 8 B
    unsigned* cnt  = (unsigned*)(packed + BSEG);              // B * 4 B
    unsigned* vmax = cnt + BSEG;                              // B * 4 B
    unsigned* bar  = vmax + BSEG;                             // barrier counter

    // Zero packed|cnt|vmax|bar in one shot (256 KB + 64 B).
    hipMemsetAsync(d_ws, 0, (size_t)BSEG * 16 + 64, stream);

    k_fused<<<dim3(NB), dim3(NT), 0, stream>>>(cand, vals, idx, out,
                                               packed, cnt, vmax, bar);
}

// Round 8
// 331.485 us; speedup vs baseline: 1.6324x; 1.6324x over previous
//
#include <hip/hip_runtime.h>

// GAQN actor, one-wave-per-segment formulation. batch_idx is SORTED, so
// segment b = [lower_bound(b), lower_bound(b+1)) found by binary search.
// cnt = hi-lo (free). vmax and gumbel-argmax via 64-lane butterfly reduces.
// ONE dispatch: no workspace, no atomics, no barriers, no memset.

#define N_ELEMS 1048576
#define BSEG    16384
#define DDIM    64

__device__ __forceinline__ unsigned rotl32(unsigned x, unsigned r) {
    return (x << r) | (x >> (32u - r));
}

#define TF_ROUND(r) { x0 += x1; x1 = rotl32(x1, (r)); x1 ^= x0; }

// Threefry-2x32, 20 rounds, key = (0, 42)
__device__ __forceinline__ void tf2x32(unsigned x0, unsigned x1,
                                       unsigned& o0, unsigned& o1) {
    const unsigned k0 = 0u, k1 = 42u;
    const unsigned ks2 = k0 ^ k1 ^ 0x1BD11BDAu;
    x0 += k0; x1 += k1;
    TF_ROUND(13) TF_ROUND(15) TF_ROUND(26) TF_ROUND(6)
    x0 += k1; x1 += ks2 + 1u;
    TF_ROUND(17) TF_ROUND(29) TF_ROUND(16) TF_ROUND(24)
    x0 += ks2; x1 += k0 + 2u;
    TF_ROUND(13) TF_ROUND(15) TF_ROUND(26) TF_ROUND(6)
    x0 += k0; x1 += k1 + 3u;
    TF_ROUND(17) TF_ROUND(29) TF_ROUND(16) TF_ROUND(24)
    x0 += k1; x1 += ks2 + 4u;
    TF_ROUND(13) TF_ROUND(15) TF_ROUND(26) TF_ROUND(6)
    x0 += ks2; x1 += k0 + 5u;
    o0 = x0; o1 = x1;
}

// jax partitionable threefry harvest (bit-exact, verified absmax=0 R3/R4/R6)
__device__ __forceinline__ float gumbel_val(unsigned i) {
    unsigned a, b;
    tf2x32(0u, i, a, b);
    unsigned bits = a ^ b;
    float f = __uint_as_float((bits >> 9) | 0x3f800000u) - 1.0f;
    const float tiny = 1.17549435e-38f;  // FLT_MIN
    float u = fmaxf(tiny, f + tiny);
    return -logf(-logf(u));
}

// Order-preserving float->uint32 encode (monotone over all finite floats)
__device__ __forceinline__ unsigned fenc(float f) {
    unsigned b = __float_as_uint(f);
    return (b & 0x80000000u) ? ~b : (b | 0x80000000u);
}

// One wave handles segment b: binary-search bounds, reduce, write row.
__global__ __launch_bounds__(256)
void k_seg(const float4* __restrict__ cand,
           const float*  __restrict__ vals,
           const int*    __restrict__ idx,
           float4*       __restrict__ out) {
    const int wave = (blockIdx.x * 256 + threadIdx.x) >> 6;   // 0 .. BSEG-1
    const int lane = threadIdx.x & 63;
    const int b    = wave;
    if (wave >= BSEG) return;

    // ---- segment bounds via two lower_bounds on sorted idx (wave-uniform,
    //      every lane computes redundantly; loads broadcast) ----
    int lo = 0, hi = N_ELEMS;                 // lower_bound(b)
    while (lo < hi) { int mid = (lo + hi) >> 1; if (idx[mid] < b) lo = mid + 1; else hi = mid; }
    const int s_lo = lo;
    hi = N_ELEMS;                             // lower_bound(b+1), start from s_lo
    while (lo < hi) { int mid = (lo + hi) >> 1; if (idx[mid] < b + 1) lo = mid + 1; else hi = mid; }
    const int s_hi = lo;
    const int n = s_hi - s_lo;                // cnt, exact, no atomics

    // ---- load this lane's elements (n<=128 fast path in registers) ----
    const int i0 = s_lo + lane;
    const int i1 = s_lo + 64 + lane;
    float v0 = 0.0f, v1 = 0.0f;
    if (i0 < s_hi) v0 = vals[i0];
    if (i1 < s_hi) v1 = vals[i1];

    // ---- vmax: running max + rare tail loop + butterfly ----
    float m = -__builtin_inff();
    if (i0 < s_hi) m = v0;
    if (i1 < s_hi) m = fmaxf(m, v1);
    for (int base = s_lo + 128; base < s_hi; base += 64) {    // ~never taken
        int i = base + lane;
        if (i < s_hi) m = fmaxf(m, vals[i]);
    }
#pragma unroll
    for (int d = 1; d < 64; d <<= 1) m = fmaxf(m, __shfl_xor(m, d, 64));

    // ---- score + packed argmax (max score, then max id — matches ref) ----
    const float c = (float)n;
    const float eps_term = 0.05f / (c - 1.0f);
    unsigned long long p = 0ull;              // 0 = "no element" sentinel
    if (i0 < s_hi) {
        float probs = ((v0 == m) ? 1.0f : 0.0f) + eps_term;
        if (isinf(probs)) probs = 1.0f;
        float s = logf(probs) + gumbel_val((unsigned)i0);
        p = ((unsigned long long)fenc(s) << 32) | (unsigned)i0;
    }
    if (i1 < s_hi) {
        float probs = ((v1 == m) ? 1.0f : 0.0f) + eps_term;
        if (isinf(probs)) probs = 1.0f;
        float s = logf(probs) + gumbel_val((unsigned)i1);
        unsigned long long q = ((unsigned long long)fenc(s) << 32) | (unsigned)i1;
        if (q > p) p = q;
    }
    for (int base = s_lo + 128; base < s_hi; base += 64) {    // ~never taken
        int i = base + lane;
        if (i < s_hi) {
            float v = vals[i];
            float probs = ((v == m) ? 1.0f : 0.0f) + eps_term;
            if (isinf(probs)) probs = 1.0f;
            float s = logf(probs) + gumbel_val((unsigned)i);
            unsigned long long q = ((unsigned long long)fenc(s) << 32) | (unsigned)i;
            if (q > p) p = q;
        }
    }
#pragma unroll
    for (int d = 1; d < 64; d <<= 1) {
        unsigned long long po = __shfl_xor(p, d, 64);
        if (po > p) p = po;
    }

    // ---- write output row r = BSEG-1-b : 16 lanes x float4 = 256 B ----
    unsigned id = (unsigned)(p & 0xFFFFFFFFull);
    if (p == 0ull || id >= N_ELEMS) id = 0u;  // empty-segment fallback
    const int r = BSEG - 1 - b;
    if (lane < 16)
        out[(size_t)r * 16 + lane] = cand[(size_t)id * 16 + lane];
}

extern "C" void kernel_launch(void* const* d_in, const int* in_sizes, int n_in,
                              void* d_out, int out_size, void* d_ws, size_t ws_size,
                              hipStream_t stream) {
    const float4* cand = (const float4*)d_in[0];
    const float*  vals = (const float*)d_in[1];
    const int*    idx  = (const int*)d_in[2];
    float4* out = (float4*)d_out;

    // One wave per segment: BSEG waves = BSEG*64 threads, 256/block.
    k_seg<<<dim3(BSEG * 64 / 256), dim3(256), 0, stream>>>(cand, vals, idx, out);
}

// Round 9
// 307.036 us; speedup vs baseline: 1.7623x; 1.0796x over previous
//
#include <hip/hip_runtime.h>

// GAQN actor, 2-dispatch: (1) linear-scan segment bounds, (2) one wave per
// segment reduces vmax + gumbel-argmax and writes the reversed gather row.
// batch_idx is SORTED. No atomics, no barriers, no memset, no binary search
// (a 40-deep dependent-load chain at cold-L2 latency was R8's 43us cost).

#define N_ELEMS 1048576
#define BSEG    16384
#define DDIM    64

__device__ __forceinline__ unsigned rotl32(unsigned x, unsigned r) {
    return (x << r) | (x >> (32u - r));
}

#define TF_ROUND(r) { x0 += x1; x1 = rotl32(x1, (r)); x1 ^= x0; }

// Threefry-2x32, 20 rounds, key = (0, 42)
__device__ __forceinline__ void tf2x32(unsigned x0, unsigned x1,
                                       unsigned& o0, unsigned& o1) {
    const unsigned k0 = 0u, k1 = 42u;
    const unsigned ks2 = k0 ^ k1 ^ 0x1BD11BDAu;
    x0 += k0; x1 += k1;
    TF_ROUND(13) TF_ROUND(15) TF_ROUND(26) TF_ROUND(6)
    x0 += k1; x1 += ks2 + 1u;
    TF_ROUND(17) TF_ROUND(29) TF_ROUND(16) TF_ROUND(24)
    x0 += ks2; x1 += k0 + 2u;
    TF_ROUND(13) TF_ROUND(15) TF_ROUND(26) TF_ROUND(6)
    x0 += k0; x1 += k1 + 3u;
    TF_ROUND(17) TF_ROUND(29) TF_ROUND(16) TF_ROUND(24)
    x0 += k1; x1 += ks2 + 4u;
    TF_ROUND(13) TF_ROUND(15) TF_ROUND(26) TF_ROUND(6)
    x0 += ks2; x1 += k0 + 5u;
    o0 = x0; o1 = x1;
}

// jax partitionable threefry harvest (bit-exact, verified absmax=0 R3-R8)
__device__ __forceinline__ float gumbel_val(unsigned i) {
    unsigned a, b;
    tf2x32(0u, i, a, b);
    unsigned bits = a ^ b;
    float f = __uint_as_float((bits >> 9) | 0x3f800000u) - 1.0f;
    const float tiny = 1.17549435e-38f;  // FLT_MIN
    float u = fmaxf(tiny, f + tiny);
    return -logf(-logf(u));
}

// Order-preserving float->uint32 encode (monotone over all finite floats)
__device__ __forceinline__ unsigned fenc(float f) {
    unsigned b = __float_as_uint(f);
    return (b & 0x80000000u) ? ~b : (b | 0x80000000u);
}

// Pass 1: segment upper bounds. hi[b] = index one past segment b's last
// element; empty segments get hi[b] = start-of-gap so n = hi[b]-hi[b-1] = 0.
// Every b in [0,BSEG) is written exactly once per call (d_ws is re-poisoned
// by the harness each iteration, so completeness matters).
__global__ __launch_bounds__(256)
void k_bounds(const int* __restrict__ idx, int* __restrict__ hi) {
    const int i = blockIdx.x * 256 + threadIdx.x;
    const int b = idx[i];
    if (i == 0) {
        for (int bb = 0; bb < b; ++bb) hi[bb] = 0;       // leading empties
    }
    const int bn = (i == N_ELEMS - 1) ? BSEG : idx[i + 1];
    if (bn != b) {
        for (int bb = b; bb < bn; ++bb) hi[bb] = i + 1;  // tail + gap empties
    }
}

// Pass 2: one wave per segment. Bounds from hi[] (two hot 64KB loads),
// vmax + packed (enc(score)<<32 | id) argmax via 64-lane butterflies.
__global__ __launch_bounds__(256)
void k_seg(const float4* __restrict__ cand,
           const float*  __restrict__ vals,
           const int*    __restrict__ hi,
           float4*       __restrict__ out) {
    const int wave = (blockIdx.x * 256 + threadIdx.x) >> 6;   // 0 .. BSEG-1
    const int lane = threadIdx.x & 63;
    const int b    = wave;

    const int s_hi = hi[b];
    const int s_lo = b ? hi[b - 1] : 0;
    const int n = s_hi - s_lo;

    // ---- this lane's elements (n<=128 fast path in registers) ----
    const int i0 = s_lo + lane;
    const int i1 = s_lo + 64 + lane;
    float v0 = 0.0f, v1 = 0.0f;
    if (i0 < s_hi) v0 = vals[i0];
    if (i1 < s_hi) v1 = vals[i1];

    // ---- vmax: running max + rare tail loop + butterfly ----
    float m = -__builtin_inff();
    if (i0 < s_hi) m = v0;
    if (i1 < s_hi) m = fmaxf(m, v1);
    for (int base = s_lo + 128; base < s_hi; base += 64) {    // ~never taken
        int i = base + lane;
        if (i < s_hi) m = fmaxf(m, vals[i]);
    }
#pragma unroll
    for (int d = 1; d < 64; d <<= 1) m = fmaxf(m, __shfl_xor(m, d, 64));

    // ---- score + packed argmax (max score, then max id — matches ref) ----
    const float c = (float)n;
    const float eps_term = 0.05f / (c - 1.0f);
    unsigned long long p = 0ull;              // 0 = "no element" sentinel
    if (i0 < s_hi) {
        float probs = ((v0 == m) ? 1.0f : 0.0f) + eps_term;
        if (isinf(probs)) probs = 1.0f;       // n==1 -> inf -> 1
        float s = logf(probs) + gumbel_val((unsigned)i0);
        p = ((unsigned long long)fenc(s) << 32) | (unsigned)i0;
    }
    if (i1 < s_hi) {
        float probs = ((v1 == m) ? 1.0f : 0.0f) + eps_term;
        if (isinf(probs)) probs = 1.0f;
        float s = logf(probs) + gumbel_val((unsigned)i1);
        unsigned long long q = ((unsigned long long)fenc(s) << 32) | (unsigned)i1;
        if (q > p) p = q;
    }
    for (int base = s_lo + 128; base < s_hi; base += 64) {    // ~never taken
        int i = base + lane;
        if (i < s_hi) {
            float v = vals[i];
            float probs = ((v == m) ? 1.0f : 0.0f) + eps_term;
            if (isinf(probs)) probs = 1.0f;
            float s = logf(probs) + gumbel_val((unsigned)i);
            unsigned long long q = ((unsigned long long)fenc(s) << 32) | (unsigned)i;
            if (q > p) p = q;
        }
    }
#pragma unroll
    for (int d = 1; d < 64; d <<= 1) {
        unsigned long long po = __shfl_xor(p, d, 64);
        if (po > p) p = po;
    }

    // ---- write output row r = BSEG-1-b : 16 lanes x float4 = 256 B ----
    unsigned id = (unsigned)(p & 0xFFFFFFFFull);
    if (p == 0ull || id >= N_ELEMS) id = 0u;  // empty segment -> cand[0]
                                              // (matches XLA clamped gather)
    const int r = BSEG - 1 - b;
    if (lane < 16)
        out[(size_t)r * 16 + lane] = cand[(size_t)id * 16 + lane];
}

extern "C" void kernel_launch(void* const* d_in, const int* in_sizes, int n_in,
                              void* d_out, int out_size, void* d_ws, size_t ws_size,
                              hipStream_t stream) {
    const float4* cand = (const float4*)d_in[0];
    const float*  vals = (const float*)d_in[1];
    const int*    idx  = (const int*)d_in[2];
    float4* out = (float4*)d_out;
    int* hi = (int*)d_ws;   // BSEG ints (64 KB), rewritten fully every call

    k_bounds<<<dim3(N_ELEMS / 256), dim3(256), 0, stream>>>(idx, hi);
    k_seg<<<dim3(BSEG * 64 / 256), dim3(256), 0, stream>>>(cand, vals, hi, out);
}